// Round 6
// baseline (282.692 us; speedup 1.0000x reference)
//
#include <hip/hip_runtime.h>
#include <hip/hip_bf16.h>
#include <cstdint>
#include <cstddef>

// ---------------------------------------------------------------------------
// ResiduesNetwork: 2-layer GNN per protein + all-pairs MLP.
// pairs@fW0 = x1@fW0[:128] + x2@fW0[128:] (precompute A,B) => dominant cost
// is h0@fW1 per pair (21 GFLOP bf16 MFMA). Phase-1 GEMMs use split bf16
// (hi+lo, 3 MFMA/k-step) for ~f32 accuracy; pair uses hi-only fW1 (absmax
// sits at the bf16 output floor 2^-8 either way).
// pair_kernel ladder: R2 80us (81KB,2blk) -> R4 58us (48KB,3blk) ->
// R5 64us (40KB but VGPR 132 still 3blk + 2x block overhead) ->
// R6: force VGPR<=128 via launch_bounds(256,4) (4-reg squeeze, NOT R3's
// 170->85 halving that spilled breg: 370MB scratch traffic).
// ---------------------------------------------------------------------------

typedef __bf16 bf16_t;
typedef __bf16 bf16x8 __attribute__((ext_vector_type(8)));
typedef float f32x4 __attribute__((ext_vector_type(4)));

static __device__ __forceinline__ f32x4 mfma_bf16(bf16x8 a, bf16x8 b, f32x4 c) {
  return __builtin_amdgcn_mfma_f32_16x16x32_bf16(a, b, c, 0, 0, 0);
}

#define N1R 800
#define NR  1600   // concat rows
#define VF  1024
#define F0  256    // conv0 out
#define F1  128    // conv1 out

// ---- fused conversion: inputs (hi/lo, x4 vectorized) + weight transposes ---
// grid.x: [0,1600) input conv (4 elems/thread); [1600,4225) weight jobs.
__global__ void conv_all(const float* __restrict__ Z1, const float* __restrict__ Z2,
                         const float* __restrict__ Wr0, const float* __restrict__ Wnr0,
                         const float* __restrict__ Wr1, const float* __restrict__ Wnr1,
                         const float* __restrict__ fW0, const float* __restrict__ fW1,
                         const float* __restrict__ fb1, const float* __restrict__ fW2,
                         const float* __restrict__ fb2,
                         bf16_t* __restrict__ Zh, bf16_t* __restrict__ Zl,
                         bf16_t* __restrict__ W0h, bf16_t* __restrict__ W0l,
                         bf16_t* __restrict__ W1h, bf16_t* __restrict__ W1l,
                         bf16_t* __restrict__ fAh, bf16_t* __restrict__ fAl,
                         bf16_t* __restrict__ fBh, bf16_t* __restrict__ fBl,
                         bf16_t* __restrict__ fW1th, float* __restrict__ fbw) {
  int bx = blockIdx.x;
  if (bx < 1600) {
    int t4 = (bx * 256 + threadIdx.x) * 4;          // elem index, x4
    int r = t4 >> 10;
    int c = t4 & (VF - 1);
    float4 v = (r < N1R) ? *(const float4*)(Z1 + r * VF + c)
                         : *(const float4*)(Z2 + (r - N1R) * VF + c);
    float vv[4] = {v.x, v.y, v.z, v.w};
    #pragma unroll
    for (int u = 0; u < 4; ++u) {
      bf16_t h = (bf16_t)vv[u];
      Zh[t4 + u] = h;
      Zl[t4 + u] = (bf16_t)(vv[u] - (float)h);
    }
    return;
  }
  int wb = bx - 1600;
  if (wb == 2624) {  // epilogue-constant table: fbw[jl*8+s]=fb1/fW2 slices
    int t = threadIdx.x;
    if (t < 128) {
      int jl = t & 15, s = t >> 4;
      fbw[jl * 8 + s] = (s < 4) ? fb1[s * 16 + jl] : fW2[(s - 4) * 16 + jl];
    } else if (t == 128) {
      fbw[128] = fb2[0];
    }
    return;
  }
  const float* src; bf16_t* dh; bf16_t* dl; int ld, lk, ln, b0;
  if      (wb < 1024) { src = Wr0;  ld = 256; lk = 10; ln = 8; dh = W0h;              dl = W0l;              b0 = 0;    }
  else if (wb < 2048) { src = Wnr0; ld = 256; lk = 10; ln = 8; dh = W0h + 256 * 1024; dl = W0l + 256 * 1024; b0 = 1024; }
  else if (wb < 2176) { src = Wr1;  ld = 128; lk = 8;  ln = 7; dh = W1h;              dl = W1l;              b0 = 2048; }
  else if (wb < 2304) { src = Wnr1; ld = 128; lk = 8;  ln = 7; dh = W1h + 128 * 256;  dl = W1l + 128 * 256;  b0 = 2176; }
  else if (wb < 2432) { src = fW0;             ld = 256; lk = 7; ln = 8; dh = fAh;    dl = fAl;              b0 = 2304; }
  else if (wb < 2560) { src = fW0 + 128 * 256; ld = 256; lk = 7; ln = 8; dh = fBh;    dl = fBl;              b0 = 2432; }
  else                { src = fW1; ld = 64;  lk = 8;  ln = 6; dh = fW1th;             dl = nullptr;          b0 = 2560; }
  int t = (wb - b0) * 256 + threadIdx.x;
  int n = t & ((1 << ln) - 1);
  int k = t >> ln;
  float v = src[k * ld + n];
  bf16_t h = (bf16_t)v;
  dh[(n << lk) + k] = h;
  if (dl) dl[(n << lk) + k] = (bf16_t)(v - (float)h);
}

// ---- split-bf16 GEMM body: C[M][N] += A[M][kslice] @ Bt[N][kslice]^T ------
// 4 waves, block tile 64x64, wave tile 32x32 (2x2 of 16x16), 3 MFMA/k-step.
static __device__ __forceinline__ void gemm_body(
    const bf16_t* __restrict__ Ah, const bf16_t* __restrict__ Al,
    const bf16_t* __restrict__ Bth, const bf16_t* __restrict__ Btl,
    const float* __restrict__ bias, float* __restrict__ C,
    int M, int N, int K, int kStart, int kLen, int row0b, int col0b) {
  int lane = threadIdx.x & 63;
  int w = threadIdx.x >> 6;
  int wr = w >> 1, wc = w & 1;
  int jl = lane & 15, hi = lane >> 4;

  int row0 = row0b + wr * 32;
  int col0 = col0b + wc * 32;

  int r0 = min(row0 + jl, M - 1);
  int r1 = min(row0 + 16 + jl, M - 1);
  int c0 = col0 + jl;
  int c1 = col0 + 16 + jl;

  const bf16_t* pA0h = Ah + (size_t)r0 * K + hi * 8;
  const bf16_t* pA1h = Ah + (size_t)r1 * K + hi * 8;
  const bf16_t* pA0l = Al + (size_t)r0 * K + hi * 8;
  const bf16_t* pA1l = Al + (size_t)r1 * K + hi * 8;
  const bf16_t* pB0h = Bth + (size_t)c0 * K + hi * 8;
  const bf16_t* pB1h = Bth + (size_t)c1 * K + hi * 8;
  const bf16_t* pB0l = Btl + (size_t)c0 * K + hi * 8;
  const bf16_t* pB1l = Btl + (size_t)c1 * K + hi * 8;

  f32x4 acc[2][2] = {};
  for (int kb = kStart; kb < kStart + kLen; kb += 32) {
    bf16x8 a0h = *(const bf16x8*)(pA0h + kb);
    bf16x8 a1h = *(const bf16x8*)(pA1h + kb);
    bf16x8 a0l = *(const bf16x8*)(pA0l + kb);
    bf16x8 a1l = *(const bf16x8*)(pA1l + kb);
    bf16x8 b0h = *(const bf16x8*)(pB0h + kb);
    bf16x8 b1h = *(const bf16x8*)(pB1h + kb);
    bf16x8 b0l = *(const bf16x8*)(pB0l + kb);
    bf16x8 b1l = *(const bf16x8*)(pB1l + kb);

    acc[0][0] = mfma_bf16(a0h, b0h, acc[0][0]);
    acc[0][1] = mfma_bf16(a0h, b1h, acc[0][1]);
    acc[1][0] = mfma_bf16(a1h, b0h, acc[1][0]);
    acc[1][1] = mfma_bf16(a1h, b1h, acc[1][1]);

    acc[0][0] = mfma_bf16(a0l, b0h, acc[0][0]);
    acc[0][1] = mfma_bf16(a0l, b1h, acc[0][1]);
    acc[1][0] = mfma_bf16(a1l, b0h, acc[1][0]);
    acc[1][1] = mfma_bf16(a1l, b1h, acc[1][1]);

    acc[0][0] = mfma_bf16(a0h, b0l, acc[0][0]);
    acc[0][1] = mfma_bf16(a0h, b1l, acc[0][1]);
    acc[1][0] = mfma_bf16(a1h, b0l, acc[1][0]);
    acc[1][1] = mfma_bf16(a1h, b1l, acc[1][1]);
  }

  #pragma unroll
  for (int m = 0; m < 2; ++m) {
    #pragma unroll
    for (int nn = 0; nn < 2; ++nn) {
      int col = col0 + nn * 16 + jl;
      float bv = bias ? bias[col] : 0.f;
      #pragma unroll
      for (int reg = 0; reg < 4; ++reg) {
        int row = row0 + m * 16 + hi * 4 + reg;
        if (row < M) C[(size_t)row * N + col] = acc[m][nn][reg] + bv;
      }
    }
  }
}

// split-K GEMM: blockIdx.z selects K-chunk, writes partial C_z.
__global__ __launch_bounds__(256) void gemm_split(
    const bf16_t* __restrict__ Ah, const bf16_t* __restrict__ Al,
    const bf16_t* __restrict__ Bth, const bf16_t* __restrict__ Btl,
    const float* __restrict__ bias, float* __restrict__ C,
    int M, int N, int K, int kLen) {
  int z = blockIdx.z;
  gemm_body(Ah, Al, Bth, Btl, bias, C + (size_t)z * M * N,
            M, N, K, z * kLen, kLen, blockIdx.y * 64, blockIdx.x * 64);
}

// dual GEMM: A' = x1@fW0top + fb0 ; B = x2@fW0bot (one launch).
__global__ __launch_bounds__(256) void gemm_dual(
    const bf16_t* __restrict__ H1h, const bf16_t* __restrict__ H1l,
    const bf16_t* __restrict__ fAh, const bf16_t* __restrict__ fAl,
    const bf16_t* __restrict__ fBh, const bf16_t* __restrict__ fBl,
    const float* __restrict__ fb0, float* __restrict__ AB) {
  int part = blockIdx.y / 13;
  int my = blockIdx.y % 13;
  gemm_body(H1h + (size_t)part * N1R * F1, H1l + (size_t)part * N1R * F1,
            part ? fBh : fAh, part ? fBl : fAl, part ? nullptr : fb0,
            AB + (size_t)part * N1R * 256, N1R, 256, F1, 0, F1,
            my * 64, blockIdx.x * 64);
}

// ---- reduce split-K partials: O = sum_z P_z ------------------------------
__global__ void reduce_k(const float* __restrict__ P, float* __restrict__ O,
                         int count4, int S) {
  int t = blockIdx.x * blockDim.x + threadIdx.x;
  if (t >= count4) return;
  float4 s = ((const float4*)P)[t];
  for (int i = 1; i < S; ++i) {
    float4 v = *(const float4*)(P + (size_t)i * count4 * 4 + (size_t)t * 4);
    s.x += v.x; s.y += v.y; s.z += v.z; s.w += v.w;
  }
  ((float4*)O)[t] = s;
}

// ---- GNN aggregate: H = relu(res + gather-sum(base)/norm), emit hi/lo -----
__global__ void agg_kernel(const float* __restrict__ RB, const int* __restrict__ nb1,
                           const int* __restrict__ nb2, bf16_t* __restrict__ Hh,
                           bf16_t* __restrict__ Hl, int F) {
  int row = blockIdx.x;
  int c = threadIdx.x;
  int S = 2 * F;
  const int* nb;
  int roff;
  if (row < N1R) { nb = nb1 + row * 10; roff = 0; }
  else           { nb = nb2 + (row - N1R) * 10; roff = N1R; }
  float s = 0.f; int cnt = 0;
  #pragma unroll
  for (int k = 0; k < 10; ++k) {
    int idx = nb[k];
    if (idx > -1) { s += RB[(size_t)(roff + idx) * S + F + c]; cnt++; }
  }
  float v = RB[(size_t)row * S + c] + s / (float)(cnt > 0 ? cnt : 1);
  v = fmaxf(v, 0.f);
  bf16_t h = (bf16_t)v;
  Hh[(size_t)row * F + c] = h;
  Hl[(size_t)row * F + c] = (bf16_t)(v - (float)h);
}

// ---- pair kernel: out[i,j] = fb2 + relu(relu(A'[i]+B[j]) @ fW1 + fb1).fW2 -
// block: 64 j (4 waves x 16) x 8 i.  B rows in regs, A' broadcast from LDS,
// fW1t hi in LDS (XOR-swizzled).  LDS 40960B exactly = 4 blocks/CU cap;
// launch_bounds(256,4) pins VGPR<=128 (natural was 132) for 4 blocks/CU.
#define IBLK 2
#define ITILE 8
__global__ __launch_bounds__(256, 4) void pair_kernel(
    const float* __restrict__ AB, const bf16_t* __restrict__ W1th,
    const float* __restrict__ fbw, float* __restrict__ out) {
  __shared__ alignas(16) unsigned char sWh[64 * 512];   // [n][512B] swizzled
  __shared__ alignas(16) float sA[ITILE * 256];

  const int tid = threadIdx.x;
  const int lane = tid & 63;
  const int w = tid >> 6;
  const int jl = lane & 15;
  const int hi = lane >> 4;
  const int j0 = blockIdx.x * 64;
  const int i0 = blockIdx.y * ITILE;

  // stage fW1t hi [64][256]bf16 -> LDS, swizzle byte^=((n&7)<<4) in-row
  #pragma unroll
  for (int s = 0; s < 8; ++s) {
    int c = tid + 256 * s;
    int n = c >> 5;
    int cb = (c & 31) << 4;
    int sw = cb ^ ((n & 7) << 4);
    *(uint4*)(sWh + n * 512 + sw) = *(const uint4*)((const unsigned char*)W1th + n * 512 + cb);
  }
  // stage A' rows i0..i0+7 (f32): 512 float4 chunks, 64 per row
  #pragma unroll
  for (int s = 0; s < 2; ++s) {
    int c = tid + 256 * s;
    int rr = c >> 6;
    int c4 = (c & 63) << 2;
    *(float4*)(sA + rr * 256 + c4) = *(const float4*)(AB + (size_t)(i0 + rr) * 256 + c4);
  }

  // B row of this lane's pair -> registers (its k-slice: 64 f32)
  int j = j0 + w * 16 + jl;
  float4 breg[16];
  {
    const float* Bp = AB + (size_t)(N1R + j) * 256;
    bool ok = (j < N1R);
    #pragma unroll
    for (int t = 0; t < 8; ++t) {
      #pragma unroll
      for (int u = 0; u < 2; ++u) {
        float4 v = make_float4(0.f, 0.f, 0.f, 0.f);
        if (ok) v = *(const float4*)(Bp + t * 32 + hi * 8 + u * 4);
        breg[t * 2 + u] = v;
      }
    }
  }

  // epilogue constants: 2 vector loads from pre-transposed table
  float4 fb1r = *(const float4*)(fbw + jl * 8);
  float4 fw2r = *(const float4*)(fbw + jl * 8 + 4);
  float bias2 = fbw[128];

  __syncthreads();

  #pragma unroll 1
  for (int ig = 0; ig < ITILE / IBLK; ++ig) {
    f32x4 acc[IBLK][4] = {};
    #pragma unroll
    for (int t = 0; t < 8; ++t) {
      // build both a-fragments first (small live set), then stream W frags
      float4 b0 = breg[t * 2], b1 = breg[t * 2 + 1];
      bf16x8 af[IBLK];
      #pragma unroll
      for (int ib = 0; ib < IBLK; ++ib) {
        const float* Ar = sA + (ig * IBLK + ib) * 256;
        float4 a0 = *(const float4*)(Ar + t * 32 + hi * 8);
        float4 a1 = *(const float4*)(Ar + t * 32 + hi * 8 + 4);
        af[ib][0] = (bf16_t)fmaxf(a0.x + b0.x, 0.f);
        af[ib][1] = (bf16_t)fmaxf(a0.y + b0.y, 0.f);
        af[ib][2] = (bf16_t)fmaxf(a0.z + b0.z, 0.f);
        af[ib][3] = (bf16_t)fmaxf(a0.w + b0.w, 0.f);
        af[ib][4] = (bf16_t)fmaxf(a1.x + b1.x, 0.f);
        af[ib][5] = (bf16_t)fmaxf(a1.y + b1.y, 0.f);
        af[ib][6] = (bf16_t)fmaxf(a1.z + b1.z, 0.f);
        af[ib][7] = (bf16_t)fmaxf(a1.w + b1.w, 0.f);
      }
      int kbyte = t * 64 + hi * 16;
      #pragma unroll
      for (int nf = 0; nf < 4; ++nf) {
        int n = nf * 16 + jl;
        bf16x8 wh = *(const bf16x8*)(sWh + n * 512 + (kbyte ^ ((n & 7) << 4)));
        #pragma unroll
        for (int ib = 0; ib < IBLK; ++ib)
          acc[ib][nf] = mfma_bf16(af[ib], wh, acc[ib][nf]);
      }
    }
    // epilogue: h1 = relu(acc + fb1); out = h1 . fW2 + fb2
    float fb1a[4] = {fb1r.x, fb1r.y, fb1r.z, fb1r.w};
    float fw2a[4] = {fw2r.x, fw2r.y, fw2r.z, fw2r.w};
    #pragma unroll
    for (int ib = 0; ib < IBLK; ++ib) {
      float part[4];
      #pragma unroll
      for (int r = 0; r < 4; ++r) {
        float ssum = 0.f;
        #pragma unroll
        for (int nf = 0; nf < 4; ++nf) {
          float h = acc[ib][nf][r] + fb1a[nf];
          h = fmaxf(h, 0.f);
          ssum += h * fw2a[nf];
        }
        part[r] = ssum;
      }
      #pragma unroll
      for (int off = 1; off < 16; off <<= 1) {
        #pragma unroll
        for (int r = 0; r < 4; ++r) part[r] += __shfl_xor(part[r], off, 64);
      }
      if (jl == 0) {
        int jo = j0 + w * 16 + hi * 4;
        if (jo < N1R) {
          float4 o = make_float4(part[0] + bias2, part[1] + bias2,
                                 part[2] + bias2, part[3] + bias2);
          *(float4*)(out + (size_t)(i0 + ig * IBLK + ib) * 800 + jo) = o;
        }
      }
    }
  }
}

// ---------------------------------------------------------------------------
extern "C" void kernel_launch(void* const* d_in, const int* in_sizes, int n_in,
                              void* d_out, int out_size, void* d_ws, size_t ws_size,
                              hipStream_t stream) {
  const float* Z1   = (const float*)d_in[0];
  const int*   nb1  = (const int*)d_in[1];
  const float* Z2   = (const float*)d_in[2];
  const int*   nb2  = (const int*)d_in[3];
  const float* Wr0  = (const float*)d_in[4];
  const float* Wnr0 = (const float*)d_in[5];
  const float* Wr1  = (const float*)d_in[6];
  const float* Wnr1 = (const float*)d_in[7];
  const float* fW0  = (const float*)d_in[8];
  const float* fb0  = (const float*)d_in[9];
  const float* fW1  = (const float*)d_in[10];
  const float* fb1  = (const float*)d_in[11];
  const float* fW2  = (const float*)d_in[12];
  const float* fb2  = (const float*)d_in[13];
  float* out = (float*)d_out;

  // workspace carve
  char* p = (char*)d_ws;
  auto alloc = [&](size_t bytes) {
    char* q = p;
    p += (bytes + 255) & ~(size_t)255;
    return q;
  };
  bf16_t* Zh    = (bf16_t*)alloc((size_t)NR * VF * 2);
  bf16_t* Zl    = (bf16_t*)alloc((size_t)NR * VF * 2);
  bf16_t* W0h   = (bf16_t*)alloc((size_t)512 * 1024 * 2);
  bf16_t* W0l   = (bf16_t*)alloc((size_t)512 * 1024 * 2);
  bf16_t* W1h   = (bf16_t*)alloc((size_t)256 * 256 * 2);
  bf16_t* W1l   = (bf16_t*)alloc((size_t)256 * 256 * 2);
  bf16_t* fAh   = (bf16_t*)alloc((size_t)256 * 128 * 2);
  bf16_t* fAl   = (bf16_t*)alloc((size_t)256 * 128 * 2);
  bf16_t* fBh   = (bf16_t*)alloc((size_t)256 * 128 * 2);
  bf16_t* fBl   = (bf16_t*)alloc((size_t)256 * 128 * 2);
  bf16_t* fW1th = (bf16_t*)alloc((size_t)64 * 256 * 2);
  float*  fbw   = (float*)alloc(129 * 4);
  float*  RB0   = (float*)alloc((size_t)NR * 512 * 4);
  bf16_t* H0h   = (bf16_t*)alloc((size_t)NR * F0 * 2);
  bf16_t* H0l   = (bf16_t*)alloc((size_t)NR * F0 * 2);
  float*  RB1   = (float*)alloc((size_t)NR * 256 * 4);
  bf16_t* H1h   = (bf16_t*)alloc((size_t)NR * F1 * 2);
  bf16_t* H1l   = (bf16_t*)alloc((size_t)NR * F1 * 2);
  float*  AB    = (float*)alloc((size_t)NR * 256 * 4);
  // split-K partial buffers (allocated last; adaptive to ws size)
  size_t part1 = (size_t)NR * 512 * 4;   // gemm1 partial (per z)
  size_t part2 = (size_t)NR * 256 * 4;   // gemm2 partial (per z)
  size_t used = (size_t)(p - (char*)d_ws);
  int S2 = (used + 4 * part2 + 1024 <= ws_size) ? 4 : 1;
  float* RB1p = (S2 > 1) ? (float*)alloc(4 * part2) : RB1;
  used = (size_t)(p - (char*)d_ws);
  int S = 1;
  if      (used + 8 * part1 + 1024 <= ws_size) S = 8;
  else if (used + 4 * part1 + 1024 <= ws_size) S = 4;
  else if (used + 2 * part1 + 1024 <= ws_size) S = 2;
  float* RB0p = (S > 1) ? (float*)alloc(S * part1) : RB0;
  (void)in_sizes; (void)n_in; (void)out_size;

  // 1. convert inputs + weights + epilogue table (one launch)
  conv_all<<<4225, 256, 0, stream>>>(Z1, Z2, Wr0, Wnr0, Wr1, Wnr1, fW0, fW1,
                                     fb1, fW2, fb2,
                                     Zh, Zl, W0h, W0l, W1h, W1l,
                                     fAh, fAl, fBh, fBl, fW1th, fbw);
  // 2. layer0 GEMM (split-K S): RB0[1600][512] = Z @ [Wr0|Wnr0]
  gemm_split<<<dim3(8, 25, S), 256, 0, stream>>>(Zh, Zl, W0h, W0l, nullptr, RB0p,
                                                 NR, 512, 1024, 1024 / S);
  if (S > 1)
    reduce_k<<<(NR * 512 / 4 + 255) / 256, 256, 0, stream>>>(RB0p, RB0, NR * 512 / 4, S);
  // 3. aggregate -> H0 (bf16 hi/lo)
  agg_kernel<<<NR, 256, 0, stream>>>(RB0, nb1, nb2, H0h, H0l, F0);
  // 4. layer1 GEMM (split-K S2): RB1[1600][256] = H0 @ [Wr1|Wnr1]
  gemm_split<<<dim3(4, 25, S2), 256, 0, stream>>>(H0h, H0l, W1h, W1l, nullptr, RB1p,
                                                  NR, 256, 256, 256 / S2);
  if (S2 > 1)
    reduce_k<<<(NR * 256 / 4 + 255) / 256, 256, 0, stream>>>(RB1p, RB1, NR * 256 / 4, S2);
  // 5. aggregate -> H1 (bf16 hi/lo)
  agg_kernel<<<NR, 128, 0, stream>>>(RB1, nb1, nb2, H1h, H1l, F1);
  // 6. A' and B in one launch
  gemm_dual<<<dim3(4, 26), 256, 0, stream>>>(H1h, H1l, fAh, fAl, fBh, fBl, fb0, AB);
  // 7. all-pairs fused MLP
  pair_kernel<<<dim3(13, 100), 256, 0, stream>>>(AB, fW1th, fbw, out);
}

// Round 7
// 113.002 us; speedup vs baseline: 2.5017x; 2.5017x over previous
//
#include <hip/hip_runtime.h>
#include <hip/hip_bf16.h>
#include <cstdint>
#include <cstddef>

// ---------------------------------------------------------------------------
// ResiduesNetwork: 2-layer GNN per protein + all-pairs MLP.
// pairs@fW0 = x1@fW0[:128] + x2@fW0[128:] (precompute A,B) => dominant cost
// is h0@fW1 per pair (21 GFLOP MFMA). Phase-1 GEMMs: split bf16 (hi+lo,
// 3 MFMA/k-step) for ~f32 accuracy.
// Pair phase is FP16 end-to-end: A',B,fW1 stored f16 (10-bit mantissa beats
// bf16's 7; values O(10) so no range risk). af = v_pk_add_f16+v_pk_max_f16,
// no cvt step, breg halves to 32 VGPR -> target natural VGPR<=128 for
// 4 blocks/CU at LDS 40960B.
// HISTORY: launch_bounds min-waves forcing spilled breg twice (R3: 370MB,
// R6: VGPR 64 / 489MB scratch traffic, 212us). Never force; shrink demand.
// ---------------------------------------------------------------------------

typedef __bf16 bf16_t;
typedef __bf16 bf16x8 __attribute__((ext_vector_type(8)));
typedef float f32x4 __attribute__((ext_vector_type(4)));
typedef _Float16 f16_t;
typedef _Float16 f16x8 __attribute__((ext_vector_type(8)));

static __device__ __forceinline__ f32x4 mfma_bf16(bf16x8 a, bf16x8 b, f32x4 c) {
  return __builtin_amdgcn_mfma_f32_16x16x32_bf16(a, b, c, 0, 0, 0);
}
static __device__ __forceinline__ f32x4 mfma_f16(f16x8 a, f16x8 b, f32x4 c) {
  return __builtin_amdgcn_mfma_f32_16x16x32_f16(a, b, c, 0, 0, 0);
}

#define N1R 800
#define NR  1600   // concat rows
#define VF  1024
#define F0  256    // conv0 out
#define F1  128    // conv1 out

// ---- fused conversion: inputs (hi/lo, x4 vectorized) + weight transposes ---
// grid.x: [0,1600) input conv (4 elems/thread); [1600,4225) weight jobs.
__global__ void conv_all(const float* __restrict__ Z1, const float* __restrict__ Z2,
                         const float* __restrict__ Wr0, const float* __restrict__ Wnr0,
                         const float* __restrict__ Wr1, const float* __restrict__ Wnr1,
                         const float* __restrict__ fW0, const float* __restrict__ fW1,
                         const float* __restrict__ fb1, const float* __restrict__ fW2,
                         const float* __restrict__ fb2,
                         bf16_t* __restrict__ Zh, bf16_t* __restrict__ Zl,
                         bf16_t* __restrict__ W0h, bf16_t* __restrict__ W0l,
                         bf16_t* __restrict__ W1h, bf16_t* __restrict__ W1l,
                         bf16_t* __restrict__ fAh, bf16_t* __restrict__ fAl,
                         bf16_t* __restrict__ fBh, bf16_t* __restrict__ fBl,
                         f16_t* __restrict__ fW1th, float* __restrict__ fbw) {
  int bx = blockIdx.x;
  if (bx < 1600) {
    int t4 = (bx * 256 + threadIdx.x) * 4;          // elem index, x4
    int r = t4 >> 10;
    int c = t4 & (VF - 1);
    float4 v = (r < N1R) ? *(const float4*)(Z1 + r * VF + c)
                         : *(const float4*)(Z2 + (r - N1R) * VF + c);
    float vv[4] = {v.x, v.y, v.z, v.w};
    #pragma unroll
    for (int u = 0; u < 4; ++u) {
      bf16_t h = (bf16_t)vv[u];
      Zh[t4 + u] = h;
      Zl[t4 + u] = (bf16_t)(vv[u] - (float)h);
    }
    return;
  }
  int wb = bx - 1600;
  if (wb >= 2560 && wb < 2624) {  // fW1 [256][64] -> f16 transposed [64][256]
    int t = (wb - 2560) * 256 + threadIdx.x;
    int n = t & 63;
    int k = t >> 6;
    fW1th[(n << 8) + k] = (f16_t)fW1[k * 64 + n];
    return;
  }
  if (wb == 2624) {  // epilogue-constant table: fbw[jl*8+s]=fb1/fW2 slices
    int t = threadIdx.x;
    if (t < 128) {
      int jl = t & 15, s = t >> 4;
      fbw[jl * 8 + s] = (s < 4) ? fb1[s * 16 + jl] : fW2[(s - 4) * 16 + jl];
    } else if (t == 128) {
      fbw[128] = fb2[0];
    }
    return;
  }
  const float* src; bf16_t* dh; bf16_t* dl; int ld, lk, ln, b0;
  if      (wb < 1024) { src = Wr0;  ld = 256; lk = 10; ln = 8; dh = W0h;              dl = W0l;              b0 = 0;    }
  else if (wb < 2048) { src = Wnr0; ld = 256; lk = 10; ln = 8; dh = W0h + 256 * 1024; dl = W0l + 256 * 1024; b0 = 1024; }
  else if (wb < 2176) { src = Wr1;  ld = 128; lk = 8;  ln = 7; dh = W1h;              dl = W1l;              b0 = 2048; }
  else if (wb < 2304) { src = Wnr1; ld = 128; lk = 8;  ln = 7; dh = W1h + 128 * 256;  dl = W1l + 128 * 256;  b0 = 2176; }
  else if (wb < 2432) { src = fW0;             ld = 256; lk = 7; ln = 8; dh = fAh;    dl = fAl;              b0 = 2304; }
  else                { src = fW0 + 128 * 256; ld = 256; lk = 7; ln = 8; dh = fBh;    dl = fBl;              b0 = 2432; }
  int t = (wb - b0) * 256 + threadIdx.x;
  int n = t & ((1 << ln) - 1);
  int k = t >> ln;
  float v = src[k * ld + n];
  bf16_t h = (bf16_t)v;
  dh[(n << lk) + k] = h;
  dl[(n << lk) + k] = (bf16_t)(v - (float)h);
}

// ---- split-bf16 GEMM body: C[M][N] += A[M][kslice] @ Bt[N][kslice]^T ------
// 4 waves, block tile 64x64, wave tile 32x32 (2x2 of 16x16), 3 MFMA/k-step.
// Output: f32 to C, or f16 to Ch (if non-null).
static __device__ __forceinline__ void gemm_body(
    const bf16_t* __restrict__ Ah, const bf16_t* __restrict__ Al,
    const bf16_t* __restrict__ Bth, const bf16_t* __restrict__ Btl,
    const float* __restrict__ bias, float* __restrict__ C,
    f16_t* __restrict__ Ch,
    int M, int N, int K, int kStart, int kLen, int row0b, int col0b) {
  int lane = threadIdx.x & 63;
  int w = threadIdx.x >> 6;
  int wr = w >> 1, wc = w & 1;
  int jl = lane & 15, hi = lane >> 4;

  int row0 = row0b + wr * 32;
  int col0 = col0b + wc * 32;

  int r0 = min(row0 + jl, M - 1);
  int r1 = min(row0 + 16 + jl, M - 1);
  int c0 = col0 + jl;
  int c1 = col0 + 16 + jl;

  const bf16_t* pA0h = Ah + (size_t)r0 * K + hi * 8;
  const bf16_t* pA1h = Ah + (size_t)r1 * K + hi * 8;
  const bf16_t* pA0l = Al + (size_t)r0 * K + hi * 8;
  const bf16_t* pA1l = Al + (size_t)r1 * K + hi * 8;
  const bf16_t* pB0h = Bth + (size_t)c0 * K + hi * 8;
  const bf16_t* pB1h = Bth + (size_t)c1 * K + hi * 8;
  const bf16_t* pB0l = Btl + (size_t)c0 * K + hi * 8;
  const bf16_t* pB1l = Btl + (size_t)c1 * K + hi * 8;

  f32x4 acc[2][2] = {};
  for (int kb = kStart; kb < kStart + kLen; kb += 32) {
    bf16x8 a0h = *(const bf16x8*)(pA0h + kb);
    bf16x8 a1h = *(const bf16x8*)(pA1h + kb);
    bf16x8 a0l = *(const bf16x8*)(pA0l + kb);
    bf16x8 a1l = *(const bf16x8*)(pA1l + kb);
    bf16x8 b0h = *(const bf16x8*)(pB0h + kb);
    bf16x8 b1h = *(const bf16x8*)(pB1h + kb);
    bf16x8 b0l = *(const bf16x8*)(pB0l + kb);
    bf16x8 b1l = *(const bf16x8*)(pB1l + kb);

    acc[0][0] = mfma_bf16(a0h, b0h, acc[0][0]);
    acc[0][1] = mfma_bf16(a0h, b1h, acc[0][1]);
    acc[1][0] = mfma_bf16(a1h, b0h, acc[1][0]);
    acc[1][1] = mfma_bf16(a1h, b1h, acc[1][1]);

    acc[0][0] = mfma_bf16(a0l, b0h, acc[0][0]);
    acc[0][1] = mfma_bf16(a0l, b1h, acc[0][1]);
    acc[1][0] = mfma_bf16(a1l, b0h, acc[1][0]);
    acc[1][1] = mfma_bf16(a1l, b1h, acc[1][1]);

    acc[0][0] = mfma_bf16(a0h, b0l, acc[0][0]);
    acc[0][1] = mfma_bf16(a0h, b1l, acc[0][1]);
    acc[1][0] = mfma_bf16(a1h, b0l, acc[1][0]);
    acc[1][1] = mfma_bf16(a1h, b1l, acc[1][1]);
  }

  #pragma unroll
  for (int m = 0; m < 2; ++m) {
    #pragma unroll
    for (int nn = 0; nn < 2; ++nn) {
      int col = col0 + nn * 16 + jl;
      float bv = bias ? bias[col] : 0.f;
      #pragma unroll
      for (int reg = 0; reg < 4; ++reg) {
        int row = row0 + m * 16 + hi * 4 + reg;
        if (row < M) {
          float val = acc[m][nn][reg] + bv;
          if (Ch) Ch[(size_t)row * N + col] = (f16_t)val;
          else    C[(size_t)row * N + col] = val;
        }
      }
    }
  }
}

// split-K GEMM: blockIdx.z selects K-chunk, writes partial C_z (f32).
__global__ __launch_bounds__(256) void gemm_split(
    const bf16_t* __restrict__ Ah, const bf16_t* __restrict__ Al,
    const bf16_t* __restrict__ Bth, const bf16_t* __restrict__ Btl,
    const float* __restrict__ bias, float* __restrict__ C,
    int M, int N, int K, int kLen) {
  int z = blockIdx.z;
  gemm_body(Ah, Al, Bth, Btl, bias, C + (size_t)z * M * N, nullptr,
            M, N, K, z * kLen, kLen, blockIdx.y * 64, blockIdx.x * 64);
}

// dual GEMM -> f16: A' = x1@fW0top + fb0 ; B = x2@fW0bot (one launch).
__global__ __launch_bounds__(256) void gemm_dual(
    const bf16_t* __restrict__ H1h, const bf16_t* __restrict__ H1l,
    const bf16_t* __restrict__ fAh, const bf16_t* __restrict__ fAl,
    const bf16_t* __restrict__ fBh, const bf16_t* __restrict__ fBl,
    const float* __restrict__ fb0, f16_t* __restrict__ ABh) {
  int part = blockIdx.y / 13;
  int my = blockIdx.y % 13;
  gemm_body(H1h + (size_t)part * N1R * F1, H1l + (size_t)part * N1R * F1,
            part ? fBh : fAh, part ? fBl : fAl, part ? nullptr : fb0,
            nullptr, ABh + (size_t)part * N1R * 256, N1R, 256, F1, 0, F1,
            my * 64, blockIdx.x * 64);
}

// ---- reduce split-K partials: O = sum_z P_z ------------------------------
__global__ void reduce_k(const float* __restrict__ P, float* __restrict__ O,
                         int count4, int S) {
  int t = blockIdx.x * blockDim.x + threadIdx.x;
  if (t >= count4) return;
  float4 s = ((const float4*)P)[t];
  for (int i = 1; i < S; ++i) {
    float4 v = *(const float4*)(P + (size_t)i * count4 * 4 + (size_t)t * 4);
    s.x += v.x; s.y += v.y; s.z += v.z; s.w += v.w;
  }
  ((float4*)O)[t] = s;
}

// ---- GNN aggregate: H = relu(res + gather-sum(base)/norm), emit hi/lo -----
__global__ void agg_kernel(const float* __restrict__ RB, const int* __restrict__ nb1,
                           const int* __restrict__ nb2, bf16_t* __restrict__ Hh,
                           bf16_t* __restrict__ Hl, int F) {
  int row = blockIdx.x;
  int c = threadIdx.x;
  int S = 2 * F;
  const int* nb;
  int roff;
  if (row < N1R) { nb = nb1 + row * 10; roff = 0; }
  else           { nb = nb2 + (row - N1R) * 10; roff = N1R; }
  float s = 0.f; int cnt = 0;
  #pragma unroll
  for (int k = 0; k < 10; ++k) {
    int idx = nb[k];
    if (idx > -1) { s += RB[(size_t)(roff + idx) * S + F + c]; cnt++; }
  }
  float v = RB[(size_t)row * S + c] + s / (float)(cnt > 0 ? cnt : 1);
  v = fmaxf(v, 0.f);
  bf16_t h = (bf16_t)v;
  Hh[(size_t)row * F + c] = h;
  Hl[(size_t)row * F + c] = (bf16_t)(v - (float)h);
}

// ---- pair kernel (FP16): out[i,j] = fb2 + relu(relu(A'[i]+B[j])@fW1+fb1).fW2
// block: 64 j (4 waves x 16) x 16 i.  B rows in regs (f16x8 x8 = 32 VGPR),
// A' broadcast from LDS (f16), fW1t f16 in LDS (XOR-swizzled).
// LDS = 32KB W + 8KB A = 40960B exactly => 4 blocks/CU cap.
#define IBLK 2
#define ITILE 16
__global__ __launch_bounds__(256) void pair_kernel(
    const f16_t* __restrict__ ABh, const f16_t* __restrict__ W1th,
    const float* __restrict__ fbw, float* __restrict__ out) {
  __shared__ alignas(16) unsigned char sWh[64 * 512];   // [n][512B] swizzled
  __shared__ alignas(16) f16_t sA[ITILE * 256];         // 8KB

  const int tid = threadIdx.x;
  const int lane = tid & 63;
  const int w = tid >> 6;
  const int jl = lane & 15;
  const int hi = lane >> 4;
  const int j0 = blockIdx.x * 64;
  const int i0 = blockIdx.y * ITILE;

  // stage fW1t f16 [64][256] -> LDS, swizzle byte^=((n&7)<<4) in-row
  #pragma unroll
  for (int s = 0; s < 8; ++s) {
    int c = tid + 256 * s;
    int n = c >> 5;
    int cb = (c & 31) << 4;
    int sw = cb ^ ((n & 7) << 4);
    *(uint4*)(sWh + n * 512 + sw) = *(const uint4*)((const unsigned char*)W1th + n * 512 + cb);
  }
  // stage A' rows i0..i0+15 (f16): 512 x 16B chunks, 32 per row
  #pragma unroll
  for (int s = 0; s < 2; ++s) {
    int c = tid + 256 * s;
    int rr = c >> 5;
    int cc = c & 31;
    *(uint4*)((unsigned char*)sA + rr * 512 + cc * 16) =
        *(const uint4*)(ABh + (size_t)(i0 + rr) * 256 + cc * 8);
  }

  // B row of this lane's pair -> registers (its k-slice: 64 f16 = 32 VGPR)
  int j = j0 + w * 16 + jl;
  f16x8 breg[8];
  {
    const f16_t* Bp = ABh + (size_t)(N1R + j) * 256;
    bool ok = (j < N1R);
    f16x8 z{};
    #pragma unroll
    for (int t = 0; t < 8; ++t)
      breg[t] = ok ? *(const f16x8*)(Bp + t * 32 + hi * 8) : z;
  }

  // epilogue constants: 2 vector loads from pre-transposed table
  float4 fb1r = *(const float4*)(fbw + jl * 8);
  float4 fw2r = *(const float4*)(fbw + jl * 8 + 4);
  float bias2 = fbw[128];

  __syncthreads();

  #pragma unroll 1
  for (int ig = 0; ig < ITILE / IBLK; ++ig) {
    f32x4 acc[IBLK][4] = {};
    #pragma unroll
    for (int t = 0; t < 8; ++t) {
      f16x8 bv = breg[t];
      f16x8 af[IBLK];
      const f16x8 Zv{};
      #pragma unroll
      for (int ib = 0; ib < IBLK; ++ib) {
        f16x8 av = *(const f16x8*)(sA + (ig * IBLK + ib) * 256 + t * 32 + hi * 8);
        af[ib] = __builtin_elementwise_max(av + bv, Zv);  // pk_add + pk_max
      }
      int kbyte = t * 64 + hi * 16;
      #pragma unroll
      for (int nf = 0; nf < 4; ++nf) {
        int n = nf * 16 + jl;
        f16x8 wh = *(const f16x8*)(sWh + n * 512 + (kbyte ^ ((n & 7) << 4)));
        #pragma unroll
        for (int ib = 0; ib < IBLK; ++ib)
          acc[ib][nf] = mfma_f16(af[ib], wh, acc[ib][nf]);
      }
    }
    // epilogue: h1 = relu(acc + fb1); out = h1 . fW2 + fb2
    float fb1a[4] = {fb1r.x, fb1r.y, fb1r.z, fb1r.w};
    float fw2a[4] = {fw2r.x, fw2r.y, fw2r.z, fw2r.w};
    #pragma unroll
    for (int ib = 0; ib < IBLK; ++ib) {
      float part[4];
      #pragma unroll
      for (int r = 0; r < 4; ++r) {
        float ssum = 0.f;
        #pragma unroll
        for (int nf = 0; nf < 4; ++nf) {
          float h = acc[ib][nf][r] + fb1a[nf];
          h = fmaxf(h, 0.f);
          ssum += h * fw2a[nf];
        }
        part[r] = ssum;
      }
      #pragma unroll
      for (int off = 1; off < 16; off <<= 1) {
        #pragma unroll
        for (int r = 0; r < 4; ++r) part[r] += __shfl_xor(part[r], off, 64);
      }
      if (jl == 0) {
        int jo = j0 + w * 16 + hi * 4;
        if (jo < N1R) {
          float4 o = make_float4(part[0] + bias2, part[1] + bias2,
                                 part[2] + bias2, part[3] + bias2);
          *(float4*)(out + (size_t)(i0 + ig * IBLK + ib) * 800 + jo) = o;
        }
      }
    }
  }
}

// ---------------------------------------------------------------------------
extern "C" void kernel_launch(void* const* d_in, const int* in_sizes, int n_in,
                              void* d_out, int out_size, void* d_ws, size_t ws_size,
                              hipStream_t stream) {
  const float* Z1   = (const float*)d_in[0];
  const int*   nb1  = (const int*)d_in[1];
  const float* Z2   = (const float*)d_in[2];
  const int*   nb2  = (const int*)d_in[3];
  const float* Wr0  = (const float*)d_in[4];
  const float* Wnr0 = (const float*)d_in[5];
  const float* Wr1  = (const float*)d_in[6];
  const float* Wnr1 = (const float*)d_in[7];
  const float* fW0  = (const float*)d_in[8];
  const float* fb0  = (const float*)d_in[9];
  const float* fW1  = (const float*)d_in[10];
  const float* fb1  = (const float*)d_in[11];
  const float* fW2  = (const float*)d_in[12];
  const float* fb2  = (const float*)d_in[13];
  float* out = (float*)d_out;

  // workspace carve
  char* p = (char*)d_ws;
  auto alloc = [&](size_t bytes) {
    char* q = p;
    p += (bytes + 255) & ~(size_t)255;
    return q;
  };
  bf16_t* Zh    = (bf16_t*)alloc((size_t)NR * VF * 2);
  bf16_t* Zl    = (bf16_t*)alloc((size_t)NR * VF * 2);
  bf16_t* W0h   = (bf16_t*)alloc((size_t)512 * 1024 * 2);
  bf16_t* W0l   = (bf16_t*)alloc((size_t)512 * 1024 * 2);
  bf16_t* W1h   = (bf16_t*)alloc((size_t)256 * 256 * 2);
  bf16_t* W1l   = (bf16_t*)alloc((size_t)256 * 256 * 2);
  bf16_t* fAh   = (bf16_t*)alloc((size_t)256 * 128 * 2);
  bf16_t* fAl   = (bf16_t*)alloc((size_t)256 * 128 * 2);
  bf16_t* fBh   = (bf16_t*)alloc((size_t)256 * 128 * 2);
  bf16_t* fBl   = (bf16_t*)alloc((size_t)256 * 128 * 2);
  f16_t*  fW1th = (f16_t*)alloc((size_t)64 * 256 * 2);
  float*  fbw   = (float*)alloc(129 * 4);
  float*  RB0   = (float*)alloc((size_t)NR * 512 * 4);
  bf16_t* H0h   = (bf16_t*)alloc((size_t)NR * F0 * 2);
  bf16_t* H0l   = (bf16_t*)alloc((size_t)NR * F0 * 2);
  float*  RB1   = (float*)alloc((size_t)NR * 256 * 4);
  bf16_t* H1h   = (bf16_t*)alloc((size_t)NR * F1 * 2);
  bf16_t* H1l   = (bf16_t*)alloc((size_t)NR * F1 * 2);
  f16_t*  ABh   = (f16_t*)alloc((size_t)NR * 256 * 2);
  // split-K partial buffers (allocated last; adaptive to ws size)
  size_t part1 = (size_t)NR * 512 * 4;   // gemm1 partial (per z)
  size_t part2 = (size_t)NR * 256 * 4;   // gemm2 partial (per z)
  size_t used = (size_t)(p - (char*)d_ws);
  int S2 = (used + 4 * part2 + 1024 <= ws_size) ? 4 : 1;
  float* RB1p = (S2 > 1) ? (float*)alloc(4 * part2) : RB1;
  used = (size_t)(p - (char*)d_ws);
  int S = 1;
  if      (used + 8 * part1 + 1024 <= ws_size) S = 8;
  else if (used + 4 * part1 + 1024 <= ws_size) S = 4;
  else if (used + 2 * part1 + 1024 <= ws_size) S = 2;
  float* RB0p = (S > 1) ? (float*)alloc(S * part1) : RB0;
  (void)in_sizes; (void)n_in; (void)out_size;

  // 1. convert inputs + weights + epilogue table (one launch)
  conv_all<<<4225, 256, 0, stream>>>(Z1, Z2, Wr0, Wnr0, Wr1, Wnr1, fW0, fW1,
                                     fb1, fW2, fb2,
                                     Zh, Zl, W0h, W0l, W1h, W1l,
                                     fAh, fAl, fBh, fBl, fW1th, fbw);
  // 2. layer0 GEMM (split-K S): RB0[1600][512] = Z @ [Wr0|Wnr0]
  gemm_split<<<dim3(8, 25, S), 256, 0, stream>>>(Zh, Zl, W0h, W0l, nullptr, RB0p,
                                                 NR, 512, 1024, 1024 / S);
  if (S > 1)
    reduce_k<<<(NR * 512 / 4 + 255) / 256, 256, 0, stream>>>(RB0p, RB0, NR * 512 / 4, S);
  // 3. aggregate -> H0 (bf16 hi/lo)
  agg_kernel<<<NR, 256, 0, stream>>>(RB0, nb1, nb2, H0h, H0l, F0);
  // 4. layer1 GEMM (split-K S2): RB1[1600][256] = H0 @ [Wr1|Wnr1]
  gemm_split<<<dim3(4, 25, S2), 256, 0, stream>>>(H0h, H0l, W1h, W1l, nullptr, RB1p,
                                                  NR, 256, 256, 256 / S2);
  if (S2 > 1)
    reduce_k<<<(NR * 256 / 4 + 255) / 256, 256, 0, stream>>>(RB1p, RB1, NR * 256 / 4, S2);
  // 5. aggregate -> H1 (bf16 hi/lo)
  agg_kernel<<<NR, 128, 0, stream>>>(RB1, nb1, nb2, H1h, H1l, F1);
  // 6. A' and B in one launch -> f16
  gemm_dual<<<dim3(4, 26), 256, 0, stream>>>(H1h, H1l, fAh, fAl, fBh, fBl, fb0, ABh);
  // 7. all-pairs fused MLP (fp16 datapath)
  pair_kernel<<<dim3(13, 50), 256, 0, stream>>>(ABh, fW1th, fbw, out);
}